// Round 14
// baseline (156.859 us; speedup 1.0000x reference)
//
#include <hip/hip_runtime.h>
#include <hip/hip_bf16.h>

// MHA forward. f32 inputs (+int32 mask), f32 output; bf16 internal pipeline.
// B=2, S=2048, D_MODEL=1024, H=16, DK=64.
// [cvt weights->bf16] -> [QKV proj GEMM z=3 (Q scaled 0.125*log2e; V transposed
// via LDS-transpose epilogue), T14 prefetch] -> [flash attn: 8-wave = 4 q-subblocks
// x 2 kv-groups, 32x32x16 MFMA, zero-shuffle P-pack via V kv-permutation, LDS dbuf
// 1-barrier/tile, defer-max, end merge] -> [cvt wo] -> [O proj].

typedef short short8  __attribute__((ext_vector_type(8)));
typedef short short4v __attribute__((ext_vector_type(4)));
typedef float f32x4   __attribute__((ext_vector_type(4)));
typedef float f32x16  __attribute__((ext_vector_type(16)));

#define D_MODEL 1024
#define SEQ     2048
#define NHEAD   16
#define DKD     64
#define HSTR    (SEQ * DKD)
#define QSCALE  0.1803368801111204f   // 0.125 * log2(e): exp2-domain softmax
#define EXP2F(x) exp2f(x)

#define MFMA16(a, b, c) __builtin_amdgcn_mfma_f32_16x16x32_bf16((a), (b), (c), 0, 0, 0)
#define MFMA32(a, b, c) __builtin_amdgcn_mfma_f32_32x32x16_bf16((a), (b), (c), 0, 0, 0)

__device__ __forceinline__ ushort f2bf(float f) {
    __hip_bfloat16 h = __float2bfloat16(f);   // RNE
    return __builtin_bit_cast(ushort, h);
}

__device__ __forceinline__ short8 frag128(const ushort* base, int row, int c0) {
    int cb = (c0 * 2) ^ ((row & 7) << 4);
    return *(const short8*)((const char*)base + row * 128 + cb);
}
__device__ __forceinline__ short8 frag256(const ushort* base, int row, int c0) {
    int cb = (c0 * 2) ^ ((row & 7) << 4);
    return *(const short8*)((const char*)base + row * 256 + cb);
}

// ---------------------------------------------------------------------------
// f32 -> bf16 weight pre-convert: 1M elems per z-slice. grid (512, nz) x 256.
// ---------------------------------------------------------------------------
__global__ __launch_bounds__(256) void cvt_w(
    const float* __restrict__ s0, const float* __restrict__ s1, const float* __restrict__ s2,
    ushort* __restrict__ dst)
{
    const int z = blockIdx.y;
    const float* s = (z == 0) ? s0 : ((z == 1) ? s1 : s2);
    ushort* d = dst + (size_t)z * 1048576;
    const int i = (blockIdx.x * 256 + threadIdx.x) * 8;
    f32x4 a = *(const f32x4*)(s + i);
    f32x4 b = *(const f32x4*)(s + i + 4);
    short8 o;
    #pragma unroll
    for (int u = 0; u < 4; ++u) { o[u] = (short)f2bf(a[u]); o[4 + u] = (short)f2bf(b[u]); }
    *(short8*)(d + i) = o;
}

// ---------------------------------------------------------------------------
// GEMM: C[4096][1024] = A[4096][1024] * W[1024][1024]^T (NT). W is bf16.
// LAYOUT 0 (QKV): z==0 -> head-split bf16 scaled QSCALE (Q); z==1 -> head-split (K);
//                 z==2 -> transposed bf16 [bh][dk][s] via LDS-transpose epilogue (V).
// LAYOUT 1: plain f32 out[m*1024+n] (O-proj).
// ---------------------------------------------------------------------------
template<int LAYOUT, int A_BF16>
__global__ __launch_bounds__(256, 3) void gemm_nt(
    const void* __restrict__ A0, const void* __restrict__ A1, const void* __restrict__ A2,
    const ushort* __restrict__ W0, const ushort* __restrict__ W1, const ushort* __restrict__ W2,
    void* __restrict__ O0, void* __restrict__ O1, void* __restrict__ O2)
{
    const int z = blockIdx.z;
    const void*   A = (z == 0) ? A0 : ((z == 1) ? A1 : A2);
    const ushort* W = (z == 0) ? W0 : ((z == 1) ? W1 : W2);
    void* O         = (z == 0) ? O0 : ((z == 1) ? O1 : O2);

    const int bm = blockIdx.x * 128;
    const int bn = blockIdx.y * 128;
    const int tid = threadIdx.x;
    const int w = tid >> 6, l = tid & 63;
    const int wr = w >> 1, wc = w & 1;

    __shared__ ushort sm[16384];

    f32x4 acc[4][4] = {};
    short8 areg[4], wreg[4];
    const int srow = tid >> 3;
    const int sc8  = (tid & 7) << 3;
    const int scb  = (sc8 * 2);

    #define GLOADT(t_) {                                                                    \
        _Pragma("unroll")                                                                   \
        for (int i = 0; i < 4; ++i) {                                                       \
            int row = i * 32 + srow;                                                        \
            if (A_BF16) {                                                                   \
                areg[i] = *(const short8*)((const ushort*)A + (size_t)(bm + row) * 1024 + (t_) * 64 + sc8); \
            } else {                                                                        \
                const float* ap = (const float*)A + (size_t)(bm + row) * 1024 + (t_) * 64 + sc8; \
                f32x4 x0 = *(const f32x4*)ap, x1 = *(const f32x4*)(ap + 4);                 \
                _Pragma("unroll")                                                           \
                for (int u = 0; u < 4; ++u) { areg[i][u] = (short)f2bf(x0[u]); areg[i][4 + u] = (short)f2bf(x1[u]); } \
            }                                                                               \
            wreg[i] = *(const short8*)(W + (size_t)(bn + row) * 1024 + (t_) * 64 + sc8);    \
        } }

    #define GWRITET() {                                                                     \
        _Pragma("unroll")                                                                   \
        for (int i = 0; i < 4; ++i) {                                                       \
            int row = i * 32 + srow;                                                        \
            int cb  = scb ^ ((row & 7) << 4);                                               \
            *(short8*)((char*)sm + row * 128 + cb) = areg[i];                               \
            *(short8*)((char*)(sm + 8192) + row * 128 + cb) = wreg[i];                      \
        } }

    GLOADT(0);
    #pragma unroll 1
    for (int t = 0; t < 16; ++t) {
        GWRITET();
        __syncthreads();
        if (t < 15) GLOADT(t + 1);

        #pragma unroll
        for (int kk = 0; kk < 2; ++kk) {
            const int c0 = kk * 32 + ((l >> 4) << 3);
            short8 af[4], bf[4];
            #pragma unroll
            for (int mi = 0; mi < 4; ++mi)
                af[mi] = frag128(sm, wr * 64 + mi * 16 + (l & 15), c0);
            #pragma unroll
            for (int ni = 0; ni < 4; ++ni)
                bf[ni] = frag128(sm + 8192, wc * 64 + ni * 16 + (l & 15), c0);
            #pragma unroll
            for (int mi = 0; mi < 4; ++mi)
                #pragma unroll
                for (int ni = 0; ni < 4; ++ni)
                    acc[mi][ni] = MFMA16(af[mi], bf[ni], acc[mi][ni]);
        }
        __syncthreads();
    }
    #undef GLOADT
    #undef GWRITET

    if (LAYOUT == 0 && z == 2) {
        // V epilogue: transpose in LDS, write [bh][dk][s] with 128B-contiguous runs.
        #pragma unroll
        for (int mi = 0; mi < 4; ++mi) {
            #pragma unroll
            for (int ni = 0; ni < 4; ++ni) {
                int n_l = wc * 64 + ni * 16 + (l & 15);
                int m0  = wr * 64 + mi * 16 + ((l >> 4) << 2);
                short4v v4;
                #pragma unroll
                for (int j = 0; j < 4; ++j) v4[j] = (short)f2bf(acc[mi][ni][j]);
                *(short4v*)((char*)sm + n_l * 256 + ((m0 * 2) ^ ((n_l & 7) << 4))) = v4;
            }
        }
        __syncthreads();
        const int row = tid >> 1, half = tid & 1;
        const int n_g = bn + row;
        const int bb  = bm >> 11;
        ushort* Op = (ushort*)O + (size_t)(bb * NHEAD + (n_g >> 6)) * HSTR
                     + (size_t)(n_g & 63) * SEQ + (bm & 2047) + half * 64;
        #pragma unroll
        for (int u = 0; u < 8; ++u) {
            short8 c = *(const short8*)((char*)sm + row * 256
                        + (((half * 64 + u * 8) * 2) ^ ((row & 7) << 4)));
            *(short8*)(Op + u * 8) = c;
        }
        return;
    }

    const float sc = (LAYOUT == 0 && z == 0) ? QSCALE : 1.0f;
    #pragma unroll
    for (int mi = 0; mi < 4; ++mi) {
        #pragma unroll
        for (int ni = 0; ni < 4; ++ni) {
            #pragma unroll
            for (int j = 0; j < 4; ++j) {
                int m = bm + wr * 64 + mi * 16 + ((l >> 4) << 2) + j;
                int n = bn + wc * 64 + ni * 16 + (l & 15);
                if (LAYOUT == 0) {
                    int b = m >> 11, s = m & 2047, h = n >> 6, dk = n & 63;
                    ((ushort*)O)[(size_t)(b * NHEAD + h) * HSTR + s * DKD + dk] = f2bf(acc[mi][ni][j] * sc);
                } else {
                    ((float*)O)[(size_t)m * 1024 + n] = acc[mi][ni][j];
                }
            }
        }
    }
}

// ---------------------------------------------------------------------------
// Flash attention, 32x32x16 MFMA. 512 thr = 8 waves = 4 q-subblocks x 2 kv-groups.
// Wave (wq,g): q-rows q0+wq*32..+31, kv-half g of each 128-tile. Swapped QK^T
// (A=K,B=Q) -> lane pair (l, l^32) holds full 64-kv P-row of q=l&31 -> 1-shfl
// softmax. V staged kv-permuted so P->A-frag pack is zero-shuffle:
// pa[kk][s] = s4[kk>>1][8*(kk&1)+s]. End: 2-way softmax-state merge via LDS.
// LDS dbuf 64KB, 1 barrier/tile, defer-max THR=8, exp2 domain.
// ---------------------------------------------------------------------------
__global__ __launch_bounds__(512, 4) void attn_fwd(
    const ushort* __restrict__ Q, const ushort* __restrict__ K, const ushort* __restrict__ Vt,
    const int* __restrict__ mask, ushort* __restrict__ ctx)
{
    const int tid = threadIdx.x;
    const int w = tid >> 6, l = tid & 63;
    const int l31 = l & 31, hi5 = l >> 5;
    const int g = w >> 2, wq = w & 3;
    const int id  = blockIdx.x;
    const int nid = (id & 7) * 64 + (id >> 3);     // XCD-chunked
    const int bh  = nid >> 4;
    const int q0  = (nid & 15) * 128;
    const int b   = bh >> 4, h = bh & 15;

    __shared__ ushort sm[2][16384];  // per buf: K [128][64] swz @0; V [64][128] swz+kvperm @8192
    __shared__ int mflag;

    if (tid == 0) mflag = 1;
    __syncthreads();
    {
        int4 m0 = ((const int4*)(mask + b * SEQ))[tid];
        if (!(m0.x && m0.y && m0.z && m0.w)) mflag = 0;
    }

    const ushort* Qh = Q  + (size_t)bh * HSTR;
    const ushort* Kh = K  + (size_t)bh * HSTR;
    const ushort* Vh = Vt + (size_t)bh * HSTR;     // [dk][s]

    // Q frags (B operand): q = q0+wq*32+l31, dk = kk*16 + hi5*8 .. +7
    short8 qf[4];
    #pragma unroll
    for (int kk = 0; kk < 4; ++kk)
        qf[kk] = *(const short8*)(Qh + (size_t)(q0 + wq * 32 + l31) * DKD + kk * 16 + hi5 * 8);

    f32x16 acc0 = {}, acc1 = {};
    float m_run = -INFINITY, l_run = 0.0f;         // state for q-row = l31 (log2 domain)

    // staging: K 2x16B/thread; V 4x8B/thread with kv-permute {0,8,4,12}
    const int kr  = tid >> 3;              // 0..63
    const int oct = tid & 7;
    const int vq  = oct & 3, vhalf = oct >> 2;
    const int kcb = oct << 4;              // K col byte
    short8  kreg[2];
    short4v vreg[4];

    #define LOADT(kt_) {                                                                   \
        kreg[0] = *(const short8*)(Kh + (size_t)((kt_) * 128 + kr) * DKD + (oct << 3));    \
        kreg[1] = *(const short8*)(Kh + (size_t)((kt_) * 128 + 64 + kr) * DKD + (oct << 3)); \
        const ushort* vp = Vh + (size_t)kr * SEQ + (kt_) * 128 + vhalf * 64 + vq * 16;     \
        vreg[0] = *(const short4v*)(vp);                                                   \
        vreg[1] = *(const short4v*)(vp + 8);                                               \
        vreg[2] = *(const short4v*)(vp + 4);                                               \
        vreg[3] = *(const short4v*)(vp + 12); }

    #define WRITET(buf_) {                                                                 \
        { int r = kr;      *(short8*)((char*)sm[buf_] + r * 128 + (kcb ^ ((r & 7) << 4))) = kreg[0]; } \
        { int r = 64 + kr; *(short8*)((char*)sm[buf_] + r * 128 + (kcb ^ ((r & 7) << 4))) = kreg[1]; } \
        { char* p = (char*)(sm[buf_] + 8192) + kr * 256;                                   \
          int pb = (vhalf * 64 + vq * 16) * 2;                                             \
          _Pragma("unroll")                                                                \
          for (int u = 0; u < 4; ++u)                                                      \
            *(short4v*)(p + ((pb + 8 * u) ^ ((kr & 7) << 4))) = vreg[u]; } }

    LOADT(0); WRITET(0);
    __syncthreads();
    const bool allones = (mflag != 0);
    const f32x16 zf = {};

    #pragma unroll 1
    for (int kt = 0; kt < 16; ++kt) {
        const int cur = kt & 1;
        const ushort* kb = sm[cur];
        const ushort* vb = sm[cur] + 8192;

        if (kt < 15) LOADT(kt + 1);

        // QK^T: s4[t] C-layout: kv = g*64 + t*32 + (reg&3)+8*(reg>>2)+4*hi5, q = l31
        f32x16 s4[2];
        __builtin_amdgcn_s_setprio(1);
        #pragma unroll
        for (int t = 0; t < 2; ++t) {
            s4[t] = MFMA32(frag128(kb, g * 64 + t * 32 + l31, hi5 * 8), qf[0], zf);
            #pragma unroll
            for (int kk = 1; kk < 4; ++kk)
                s4[t] = MFMA32(frag128(kb, g * 64 + t * 32 + l31, kk * 16 + hi5 * 8), qf[kk], s4[t]);
        }
        __builtin_amdgcn_s_setprio(0);

        // mask (exact masked_fill, pre-max)
        if (!allones) {
            const int* mrow = mask + b * SEQ + kt * 128 + g * 64 + 4 * hi5;
            #pragma unroll
            for (int t = 0; t < 2; ++t)
                #pragma unroll
                for (int r4 = 0; r4 < 4; ++r4) {
                    int4 mv = *(const int4*)(mrow + (t * 4 + r4) * 8);
                    s4[t][r4 * 4 + 0] = mv.x ? s4[t][r4 * 4 + 0] : -1e9f;
                    s4[t][r4 * 4 + 1] = mv.y ? s4[t][r4 * 4 + 1] : -1e9f;
                    s4[t][r4 * 4 + 2] = mv.z ? s4[t][r4 * 4 + 2] : -1e9f;
                    s4[t][r4 * 4 + 3] = mv.w ? s4[t][r4 * 4 + 3] : -1e9f;
                }
        }

        // row max (lane pair holds full 64-kv row): tree + 1 shfl
        float tm = s4[0][0];
        #pragma unroll
        for (int i = 1; i < 16; ++i) tm = fmaxf(tm, s4[0][i]);
        #pragma unroll
        for (int i = 0; i < 16; ++i) tm = fmaxf(tm, s4[1][i]);
        tm = fmaxf(tm, __shfl_xor(tm, 32));

        if (!__all(tm <= m_run + 8.0f)) {  // defer-max
            float mnew = fmaxf(m_run, tm);
            float c = EXP2F(m_run - mnew);
            m_run = mnew;
            l_run *= c;
            float cj[16];
            #pragma unroll
            for (int r = 0; r < 16; ++r)
                cj[r] = __shfl(c, (l & 32) | ((r & 3) + 8 * (r >> 2) + 4 * hi5));
            #pragma unroll
            for (int r = 0; r < 16; ++r) { acc0[r] *= cj[r]; acc1[r] *= cj[r]; }
        }

        float rs = 0.0f;
        #pragma unroll
        for (int t = 0; t < 2; ++t)
            #pragma unroll
            for (int i = 0; i < 16; ++i) { s4[t][i] = EXP2F(s4[t][i] - m_run); rs += s4[t][i]; }
        rs += __shfl_xor(rs, 32);
        l_run += rs;

        // zero-shuffle P pack: pa[kk][s] = s4[kk>>1][8*(kk&1)+s]
        short8 pa[4];
        #pragma unroll
        for (int kk = 0; kk < 4; ++kk)
            #pragma unroll
            for (int s = 0; s < 8; ++s)
                pa[kk][s] = (short)f2bf(s4[kk >> 1][8 * (kk & 1) + s]);

        if (kt < 15) WRITET(cur ^ 1);

        // PV: acc C-layout: q = (reg&3)+8*(reg>>2)+4*hi5, dk = ni*32 + l31
        __builtin_amdgcn_s_setprio(1);
        #pragma unroll
        for (int kk = 0; kk < 4; ++kk) {
            acc0 = MFMA32(pa[kk], frag256(vb, l31,      g * 64 + kk * 16 + hi5 * 8), acc0);
            acc1 = MFMA32(pa[kk], frag256(vb, 32 + l31, g * 64 + kk * 16 + hi5 * 8), acc1);
        }
        __builtin_amdgcn_s_setprio(0);

        __syncthreads();
    }
    #undef LOADT
    #undef WRITET

    // --- 2-way kv-group merge + epilogue
    __syncthreads();
    float* mls  = (float*)sm;            // [4 wq][64 lane][2]
    float* accs = (float*)sm + 512;      // [4 wq][64 lane][32]
    if (g == 1) {
        float* mp = mls + (wq * 64 + l) * 2;
        mp[0] = m_run; mp[1] = l_run;
        float* ap = accs + (wq * 64 + l) * 32;
        #pragma unroll
        for (int r = 0; r < 16; ++r) { ap[r] = acc0[r]; ap[16 + r] = acc1[r]; }
    }
    __syncthreads();
    if (g == 0) {
        const float* mp = mls + (wq * 64 + l) * 2;
        float mB = mp[0], lB = mp[1];
        float ms = fmaxf(m_run, mB);
        float cA = EXP2F(m_run - ms), cB = EXP2F(mB - ms);
        float li = 1.0f / (cA * l_run + cB * lB);
        float sA = cA * li, sB = cB * li;
        const float* ap = accs + (wq * 64 + l) * 32;
        #pragma unroll
        for (int r = 0; r < 16; ++r) {
            int qp = (r & 3) + 8 * (r >> 2) + 4 * hi5;
            float sAr = __shfl(sA, (l & 32) | qp);
            float sBr = __shfl(sB, (l & 32) | qp);
            float v0 = sAr * acc0[r] + sBr * ap[r];
            float v1 = sAr * acc1[r] + sBr * ap[16 + r];
            int qg = q0 + wq * 32 + qp;
            ctx[(size_t)(b * SEQ + qg) * D_MODEL + h * DKD + l31]      = f2bf(v0);
            ctx[(size_t)(b * SEQ + qg) * D_MODEL + h * DKD + 32 + l31] = f2bf(v1);
        }
    }
}

__global__ void ws_sentinel(float* __restrict__ out, int n, float code) {
    int i = blockIdx.x * blockDim.x + threadIdx.x;
    if (i < n) out[i] = (i == 0) ? code : 0.0f;
}

// ---------------------------------------------------------------------------
extern "C" void kernel_launch(void* const* d_in, const int* in_sizes, int n_in,
                              void* d_out, int out_size, void* d_ws, size_t ws_size,
                              hipStream_t stream) {
    const float* q    = (const float*)d_in[0];
    const float* k    = (const float*)d_in[1];
    const float* v    = (const float*)d_in[2];
    const int*   mask = (const int*)d_in[3];
    const float* wq   = (const float*)d_in[4];
    const float* wk   = (const float*)d_in[5];
    const float* wv   = (const float*)d_in[6];
    const float* wo   = (const float*)d_in[7];
    float* out = (float*)d_out;

    if (ws_size < (size_t)33554432) {
        float code = 100.0f + (float)(ws_size >> 20);
        ws_sentinel<<<(out_size + 255) / 256, 256, 0, stream>>>(out, out_size, code);
        return;
    }

    ushort* ws = (ushort*)d_ws;
    ushort* Qb = ws;                       // [bh][s][dk] bf16 (scaled QSCALE); later: wo bf16
    ushort* Kb = ws + 4194304;             // [bh][s][dk]
    ushort* Vb = ws + 8388608;             // [bh][dk][s]  (transposed)
    ushort* Cb = ws + 12582912;            // first: wq/wk/wv bf16; then context [b,s,d] bf16

    dim3 blk(256, 1, 1);
    cvt_w<<<dim3(512, 3), blk, 0, stream>>>(wq, wk, wv, Cb);
    gemm_nt<0, 0><<<dim3(32, 8, 3), blk, 0, stream>>>(
        q, k, v, Cb, Cb + 1048576, Cb + 2097152, Qb, Kb, Vb);
    attn_fwd<<<dim3(512, 1, 1), dim3(512, 1, 1), 0, stream>>>(Qb, Kb, Vb, mask, Cb);
    cvt_w<<<dim3(512, 1), blk, 0, stream>>>(wo, wo, wo, Qb);
    gemm_nt<1, 1><<<dim3(32, 8, 1), blk, 0, stream>>>(
        Cb, Cb, Cb, Qb, Qb, Qb, out, out, out);
}

// Round 15
// 139.306 us; speedup vs baseline: 1.1260x; 1.1260x over previous
//
#include <hip/hip_runtime.h>
#include <hip/hip_bf16.h>

// MHA forward. f32 inputs (+int32 mask), f32 output; bf16 internal pipeline.
// B=2, S=2048, D_MODEL=1024, H=16, DK=64.
// [cvt weights->bf16] -> [QKV proj GEMM z=3 (Q scaled 0.125*log2e; V transposed
// via LDS-transpose epilogue), T14 A-prefetch + W via global_load_lds dbuf] ->
// [flash attn r13: 8-wave QBLK=128, 16x16 MFMA, LDS dbuf 1-barrier/tile,
// defer-max] -> [cvt wo] -> [O proj].

typedef short short8  __attribute__((ext_vector_type(8)));
typedef short short4v __attribute__((ext_vector_type(4)));
typedef float f32x4   __attribute__((ext_vector_type(4)));

#define D_MODEL 1024
#define SEQ     2048
#define NHEAD   16
#define DKD     64
#define HSTR    (SEQ * DKD)
#define QSCALE  0.1803368801111204f   // 0.125 * log2(e): exp2-domain softmax
#define EXP2F(x) exp2f(x)

#define MFMA16(a, b, c) __builtin_amdgcn_mfma_f32_16x16x32_bf16((a), (b), (c), 0, 0, 0)

#define GLDS16(gp, lp) __builtin_amdgcn_global_load_lds( \
    (const __attribute__((address_space(1))) void*)(gp), \
    (__attribute__((address_space(3))) void*)(lp), 16, 0, 0)

__device__ __forceinline__ ushort f2bf(float f) {
    __hip_bfloat16 h = __float2bfloat16(f);   // RNE
    return __builtin_bit_cast(ushort, h);
}

__device__ __forceinline__ short8 frag128(const ushort* base, int row, int c0) {
    int cb = (c0 * 2) ^ ((row & 7) << 4);
    return *(const short8*)((const char*)base + row * 128 + cb);
}
__device__ __forceinline__ short8 frag256(const ushort* base, int row, int c0) {
    int cb = (c0 * 2) ^ ((row & 7) << 4);
    return *(const short8*)((const char*)base + row * 256 + cb);
}

// ---------------------------------------------------------------------------
// f32 -> bf16 weight pre-convert: 1M elems per z-slice. grid (512, nz) x 256.
// ---------------------------------------------------------------------------
__global__ __launch_bounds__(256) void cvt_w(
    const float* __restrict__ s0, const float* __restrict__ s1, const float* __restrict__ s2,
    ushort* __restrict__ dst)
{
    const int z = blockIdx.y;
    const float* s = (z == 0) ? s0 : ((z == 1) ? s1 : s2);
    ushort* d = dst + (size_t)z * 1048576;
    const int i = (blockIdx.x * 256 + threadIdx.x) * 8;
    f32x4 a = *(const f32x4*)(s + i);
    f32x4 b = *(const f32x4*)(s + i + 4);
    short8 o;
    #pragma unroll
    for (int u = 0; u < 4; ++u) { o[u] = (short)f2bf(a[u]); o[4 + u] = (short)f2bf(b[u]); }
    *(short8*)(d + i) = o;
}

// ---------------------------------------------------------------------------
// GEMM: C[4096][1024] = A[4096][1024] * W[1024][1024]^T (NT). W is bf16.
// W staged via global_load_lds (16B) into double-buffered LDS with pre-swizzled
// global source (linear LDS dest; read-side XOR matches source permutation).
// A reg-staged (f32->bf16 cvt inline for LAYOUT 0).
// LAYOUT 0 (QKV): z==0 -> head-split bf16 scaled QSCALE (Q); z==1 -> head-split (K);
//                 z==2 -> transposed bf16 [bh][dk][s] via LDS-transpose epilogue (V).
// LAYOUT 1: plain f32 out[m*1024+n] (O-proj).
// ---------------------------------------------------------------------------
template<int LAYOUT, int A_BF16>
__global__ __launch_bounds__(256, 3) void gemm_nt(
    const void* __restrict__ A0, const void* __restrict__ A1, const void* __restrict__ A2,
    const ushort* __restrict__ W0, const ushort* __restrict__ W1, const ushort* __restrict__ W2,
    void* __restrict__ O0, void* __restrict__ O1, void* __restrict__ O2)
{
    const int z = blockIdx.z;
    const void*   A = (z == 0) ? A0 : ((z == 1) ? A1 : A2);
    const ushort* W = (z == 0) ? W0 : ((z == 1) ? W1 : W2);
    void* O         = (z == 0) ? O0 : ((z == 1) ? O1 : O2);

    const int bm = blockIdx.x * 128;
    const int bn = blockIdx.y * 128;
    const int tid = threadIdx.x;
    const int w = tid >> 6, l = tid & 63;
    const int wr = w >> 1, wc = w & 1;

    __shared__ ushort smA[8192];      // A tile [128][64] swizzled
    __shared__ ushort smW[2][8192];   // W tile dbuf, filled by global_load_lds

    f32x4 acc[4][4] = {};
    short8 areg[4];
    const int srow = tid >> 3;
    const int sc8  = (tid & 7) << 3;
    const int scb  = (sc8 * 2);

    #define GLOADA(t_) {                                                                    \
        _Pragma("unroll")                                                                   \
        for (int i = 0; i < 4; ++i) {                                                       \
            int row = i * 32 + srow;                                                        \
            if (A_BF16) {                                                                   \
                areg[i] = *(const short8*)((const ushort*)A + (size_t)(bm + row) * 1024 + (t_) * 64 + sc8); \
            } else {                                                                        \
                const float* ap = (const float*)A + (size_t)(bm + row) * 1024 + (t_) * 64 + sc8; \
                f32x4 x0 = *(const f32x4*)ap, x1 = *(const f32x4*)(ap + 4);                 \
                _Pragma("unroll")                                                           \
                for (int u = 0; u < 4; ++u) { areg[i][u] = (short)f2bf(x0[u]); areg[i][4 + u] = (short)f2bf(x1[u]); } \
            }                                                                               \
        } }

    #define GWRITEA() {                                                                     \
        _Pragma("unroll")                                                                   \
        for (int i = 0; i < 4; ++i) {                                                       \
            int row = i * 32 + srow;                                                        \
            int cb  = scb ^ ((row & 7) << 4);                                               \
            *(short8*)((char*)smA + row * 128 + cb) = areg[i];                              \
        } }

    // W: LDS linear dest (wave-uniform base + lane*16B); source col inverse-swizzled
    #define GLDSW(t_, buf_) {                                                               \
        _Pragma("unroll")                                                                   \
        for (int i = 0; i < 4; ++i) {                                                       \
            int flat = i * 256 + tid;                                                       \
            int row  = flat >> 3;                                                           \
            int pcb  = (flat & 7) << 4;                                                     \
            int sc   = (pcb ^ ((row & 7) << 4)) >> 1;                                       \
            GLDS16(W + (size_t)(bn + row) * 1024 + (t_) * 64 + sc,                          \
                   &smW[buf_][(i * 4 + w) * 512]);                                          \
        } }

    GLOADA(0);
    GLDSW(0, 0);
    #pragma unroll 1
    for (int t = 0; t < 16; ++t) {
        GWRITEA();
        __syncthreads();                    // A[t] visible; vmcnt drained -> W[t] in smW[t&1]
        if (t < 15) { GLOADA(t + 1); GLDSW(t + 1, (t + 1) & 1); }

        const ushort* wb = smW[t & 1];
        #pragma unroll
        for (int kk = 0; kk < 2; ++kk) {
            const int c0 = kk * 32 + ((l >> 4) << 3);
            short8 af[4], bf[4];
            #pragma unroll
            for (int mi = 0; mi < 4; ++mi)
                af[mi] = frag128(smA, wr * 64 + mi * 16 + (l & 15), c0);
            #pragma unroll
            for (int ni = 0; ni < 4; ++ni)
                bf[ni] = frag128(wb, wc * 64 + ni * 16 + (l & 15), c0);
            #pragma unroll
            for (int mi = 0; mi < 4; ++mi)
                #pragma unroll
                for (int ni = 0; ni < 4; ++ni)
                    acc[mi][ni] = MFMA16(af[mi], bf[ni], acc[mi][ni]);
        }
        __syncthreads();                    // A reads done before next GWRITEA
    }
    #undef GLOADA
    #undef GWRITEA
    #undef GLDSW

    if (LAYOUT == 0 && z == 2) {
        // V epilogue: transpose via 32KB smW region, write [bh][dk][s] contiguous.
        ushort* tb = &smW[0][0];
        #pragma unroll
        for (int mi = 0; mi < 4; ++mi) {
            #pragma unroll
            for (int ni = 0; ni < 4; ++ni) {
                int n_l = wc * 64 + ni * 16 + (l & 15);
                int m0  = wr * 64 + mi * 16 + ((l >> 4) << 2);
                short4v v4;
                #pragma unroll
                for (int j = 0; j < 4; ++j) v4[j] = (short)f2bf(acc[mi][ni][j]);
                *(short4v*)((char*)tb + n_l * 256 + ((m0 * 2) ^ ((n_l & 7) << 4))) = v4;
            }
        }
        __syncthreads();
        const int row = tid >> 1, half = tid & 1;
        const int n_g = bn + row;
        const int bb  = bm >> 11;
        ushort* Op = (ushort*)O + (size_t)(bb * NHEAD + (n_g >> 6)) * HSTR
                     + (size_t)(n_g & 63) * SEQ + (bm & 2047) + half * 64;
        #pragma unroll
        for (int u = 0; u < 8; ++u) {
            short8 c = *(const short8*)((char*)tb + row * 256
                        + (((half * 64 + u * 8) * 2) ^ ((row & 7) << 4)));
            *(short8*)(Op + u * 8) = c;
        }
        return;
    }

    const float sc = (LAYOUT == 0 && z == 0) ? QSCALE : 1.0f;
    #pragma unroll
    for (int mi = 0; mi < 4; ++mi) {
        #pragma unroll
        for (int ni = 0; ni < 4; ++ni) {
            #pragma unroll
            for (int j = 0; j < 4; ++j) {
                int m = bm + wr * 64 + mi * 16 + ((l >> 4) << 2) + j;
                int n = bn + wc * 64 + ni * 16 + (l & 15);
                if (LAYOUT == 0) {
                    int b = m >> 11, s = m & 2047, h = n >> 6, dk = n & 63;
                    ((ushort*)O)[(size_t)(b * NHEAD + h) * HSTR + s * DKD + dk] = f2bf(acc[mi][ni][j] * sc);
                } else {
                    ((float*)O)[(size_t)m * 1024 + n] = acc[mi][ni][j];
                }
            }
        }
    }
}

// ---------------------------------------------------------------------------
// Flash attention (round-13 version). 512 thr = 8 waves, QBLK=128 (16 q-rows/wave),
// KVBLK=128, LDS double-buffer (64 KB) -> ONE barrier per tile. Swapped QK^T,
// exp2-domain in-register softmax, defer-max THR=8, zero-C MFMA s4 init.
// Grid 512 (XCD-chunked, 2 bh per XCD).
// ---------------------------------------------------------------------------
__global__ __launch_bounds__(512, 4) void attn_fwd(
    const ushort* __restrict__ Q, const ushort* __restrict__ K, const ushort* __restrict__ Vt,
    const int* __restrict__ mask, ushort* __restrict__ ctx)
{
    const int tid = threadIdx.x;
    const int w = tid >> 6, l = tid & 63;
    const int hi = l >> 4, lo = l & 15;
    const int id  = blockIdx.x;
    const int nid = (id & 7) * 64 + (id >> 3);     // 8 XCDs x 64 blocks
    const int bh  = nid >> 4;
    const int q0  = (nid & 15) * 128;
    const int b   = bh >> 4, h = bh & 15;

    __shared__ ushort sm[2][16384];  // per buf: K [128][64] swz @0; V [64][128] swz @8192
    __shared__ int mflag;

    if (tid == 0) mflag = 1;
    __syncthreads();
    {
        int4 m0 = ((const int4*)(mask + b * SEQ))[tid];
        if (!(m0.x && m0.y && m0.z && m0.w)) mflag = 0;
    }

    const ushort* Qh = Q  + (size_t)bh * HSTR;
    const ushort* Kh = K  + (size_t)bh * HSTR;
    const ushort* Vh = Vt + (size_t)bh * HSTR;     // [dk][s]

    short8 qf[2];
    #pragma unroll
    for (int kk = 0; kk < 2; ++kk)
        qf[kk] = *(const short8*)(Qh + (size_t)(q0 + w * 16 + lo) * DKD + kk * 32 + hi * 8);

    f32x4 acc_o[4] = {};
    float m_run = -INFINITY, l_run = 0.0f;

    const int kr = tid >> 3;               // 0..63
    const int kc = (tid & 7) << 3;
    const int vr = tid >> 4;               // 0..31
    const int vkpb = (tid & 15) << 4;

    short8  kreg[2];
    short4v vreg0[2], vreg1[2];

    #define LOADT(kt_) {                                                                   \
        _Pragma("unroll")                                                                  \
        for (int i = 0; i < 2; ++i)                                                        \
            kreg[i] = *(const short8*)(Kh + (size_t)((kt_) * 128 + i * 64 + kr) * DKD + kc); \
        _Pragma("unroll")                                                                  \
        for (int i = 0; i < 2; ++i) {                                                      \
            const ushort* vp = Vh + (size_t)(i * 32 + vr) * SEQ + (kt_) * 128 + ((tid >> 2) & 3) * 32 + (tid & 3) * 4; \
            vreg0[i] = *(const short4v*)(vp);                                              \
            vreg1[i] = *(const short4v*)(vp + 16); } }

    #define WRITET(buf_) {                                                                 \
        _Pragma("unroll")                                                                  \
        for (int i = 0; i < 2; ++i) {                                                      \
            int r = i * 64 + kr;                                                           \
            *(short8*)((char*)sm[buf_] + r * 128 + ((kc * 2) ^ ((r & 7) << 4))) = kreg[i]; } \
        _Pragma("unroll")                                                                  \
        for (int i = 0; i < 2; ++i) {                                                      \
            int r = i * 32 + vr;                                                           \
            char* p = (char*)(sm[buf_] + 8192) + r * 256 + (vkpb ^ ((r & 7) << 4));        \
            *(short4v*)(p)     = vreg0[i];                                                 \
            *(short4v*)(p + 8) = vreg1[i]; } }

    LOADT(0); WRITET(0);
    __syncthreads();                       // buf0 staged + mflag final
    const bool allones = (mflag != 0);
    const f32x4 zf = {};

    #define HALF(nb_) {                                                                    \
        f32x4* s = s4 + 4 * (nb_);                                                         \
        if (!allones) {                                                                    \
            const int* mrow = mask + b * SEQ + kt * 128 + (nb_) * 64 + hi * 4;             \
            _Pragma("unroll")                                                              \
            for (int ni = 0; ni < 4; ++ni) {                                               \
                int4 mv = *(const int4*)(mrow + ni * 16);                                  \
                s[ni][0] = mv.x ? s[ni][0] : -1e9f;                                        \
                s[ni][1] = mv.y ? s[ni][1] : -1e9f;                                        \
                s[ni][2] = mv.z ? s[ni][2] : -1e9f;                                        \
                s[ni][3] = mv.w ? s[ni][3] : -1e9f;                                        \
            }                                                                              \
        }                                                                                  \
        float t0 = fmaxf(fmaxf(s[0][0], s[0][1]), fmaxf(s[0][2], s[0][3]));                \
        float t1 = fmaxf(fmaxf(s[1][0], s[1][1]), fmaxf(s[1][2], s[1][3]));                \
        float t2 = fmaxf(fmaxf(s[2][0], s[2][1]), fmaxf(s[2][2], s[2][3]));                \
        float t3 = fmaxf(fmaxf(s[3][0], s[3][1]), fmaxf(s[3][2], s[3][3]));                \
        float t = fmaxf(fmaxf(t0, t1), fmaxf(t2, t3));                                     \
        t = fmaxf(t, __shfl_xor(t, 16));                                                   \
        t = fmaxf(t, __shfl_xor(t, 32));                                                   \
        if (!__all(t <= m_run + 8.0f)) {   /* defer-max: rescale only on real growth */    \
            float mnew = fmaxf(m_run, t);                                                  \
            float c = EXP2F(m_run - mnew);                                                 \
            m_run = mnew;                                                                  \
            l_run *= c;                                                                    \
            float cj[4];                                                                   \
            _Pragma("unroll")                                                              \
            for (int j = 0; j < 4; ++j) cj[j] = __shfl(c, (l & 48) | (hi * 4 + j));        \
            _Pragma("unroll")                                                              \
            for (int ni = 0; ni < 4; ++ni)                                                 \
                _Pragma("unroll")                                                          \
                for (int j = 0; j < 4; ++j) acc_o[ni][j] *= cj[j];                         \
        }                                                                                  \
        float rsA = 0.0f;                                                                  \
        _Pragma("unroll")                                                                  \
        for (int ni = 0; ni < 4; ++ni) {                                                   \
            _Pragma("unroll")                                                              \
            for (int j = 0; j < 4; ++j) s[ni][j] = EXP2F(s[ni][j] - m_run);                \
            rsA += (s[ni][0] + s[ni][1]) + (s[ni][2] + s[ni][3]);                          \
        }                                                                                  \
        rsA += __shfl_xor(rsA, 16);                                                        \
        rsA += __shfl_xor(rsA, 32);                                                        \
        l_run += rsA;                                                                      \
        short8 pa[2];                                                                      \
        _Pragma("unroll")                                                                  \
        for (int kk = 0; kk < 2; ++kk) {                                                   \
            _Pragma("unroll")                                                              \
            for (int j = 0; j < 4; ++j) {                                                  \
                pa[kk][j]     = (short)f2bf(s[2 * kk][j]);                                 \
                pa[kk][4 + j] = (short)f2bf(s[2 * kk + 1][j]);                             \
            }                                                                              \
        }                                                                                  \
        __builtin_amdgcn_s_setprio(1);                                                     \
        _Pragma("unroll")                                                                  \
        for (int kk = 0; kk < 2; ++kk) {                                                   \
            const int c0 = ((nb_) * 2 + kk) * 32 + hi * 8;                                 \
            _Pragma("unroll")                                                              \
            for (int ni = 0; ni < 4; ++ni) {                                               \
                short8 vf = frag256(vb, ni * 16 + lo, c0);                                 \
                acc_o[ni] = MFMA16(pa[kk], vf, acc_o[ni]);                                 \
            }                                                                              \
        }                                                                                  \
        __builtin_amdgcn_s_setprio(0); }

    #pragma unroll 1
    for (int kt = 0; kt < 16; ++kt) {
        const int cur = kt & 1;
        const ushort* kb = sm[cur];
        const ushort* vb = sm[cur] + 8192;

        if (kt < 15) LOADT(kt + 1);        // global->regs, lands under QK^T+SM(A)

        // QK^T: s4[ni] C-layout: kv = ni*16 + hi*4 + j, q = lo. Zero-C init.
        f32x4 s4[8];
        __builtin_amdgcn_s_setprio(1);
        #pragma unroll
        for (int ni = 0; ni < 8; ++ni)
            s4[ni] = MFMA16(frag128(kb, ni * 16 + lo, hi * 8), qf[0], zf);
        #pragma unroll
        for (int ni = 0; ni < 8; ++ni)
            s4[ni] = MFMA16(frag128(kb, ni * 16 + lo, 32 + hi * 8), qf[1], s4[ni]);
        __builtin_amdgcn_s_setprio(0);

        HALF(0)
        if (kt < 15) WRITET(cur ^ 1);      // regs->other buffer (free: tile kt-1's reads done)
        HALF(1)

        __syncthreads();                   // single barrier: buf[cur] reads + buf[cur^1] writes done
    }
    #undef HALF
    #undef LOADT
    #undef WRITET

    float inv = 1.0f / l_run;
    float invj[4];
    #pragma unroll
    for (int j = 0; j < 4; ++j)
        invj[j] = __shfl(inv, (l & 48) | (hi * 4 + j));
    #pragma unroll
    for (int ni = 0; ni < 4; ++ni)
        #pragma unroll
        for (int j = 0; j < 4; ++j) {
            int qg = q0 + w * 16 + hi * 4 + j;
            ctx[(size_t)(b * SEQ + qg) * D_MODEL + h * DKD + ni * 16 + lo] = f2bf(acc_o[ni][j] * invj[j]);
        }
}

__global__ void ws_sentinel(float* __restrict__ out, int n, float code) {
    int i = blockIdx.x * blockDim.x + threadIdx.x;
    if (i < n) out[i] = (i == 0) ? code : 0.0f;
}

// ---------------------------------------------------------------------------
extern "C" void kernel_launch(void* const* d_in, const int* in_sizes, int n_in,
                              void* d_out, int out_size, void* d_ws, size_t ws_size,
                              hipStream_t stream) {
    const float* q    = (const float*)d_in[0];
    const float* k    = (const float*)d_in[1];
    const float* v    = (const float*)d_in[2];
    const int*   mask = (const int*)d_in[3];
    const float* wq   = (const float*)d_in[4];
    const float* wk   = (const float*)d_in[5];
    const float* wv   = (const float*)d_in[6];
    const float* wo   = (const float*)d_in[7];
    float* out = (float*)d_out;

    if (ws_size < (size_t)33554432) {
        float code = 100.0f + (float)(ws_size >> 20);
        ws_sentinel<<<(out_size + 255) / 256, 256, 0, stream>>>(out, out_size, code);
        return;
    }

    ushort* ws = (ushort*)d_ws;
    ushort* Qb = ws;                       // [bh][s][dk] bf16 (scaled QSCALE); later: wo bf16
    ushort* Kb = ws + 4194304;             // [bh][s][dk]
    ushort* Vb = ws + 8388608;             // [bh][dk][s]  (transposed)
    ushort* Cb = ws + 12582912;            // first: wq/wk/wv bf16; then context [b,s,d] bf16

    dim3 blk(256, 1, 1);
    cvt_w<<<dim3(512, 3), blk, 0, stream>>>(wq, wk, wv, Cb);
    gemm_nt<0, 0><<<dim3(32, 8, 3), blk, 0, stream>>>(
        q, k, v, Cb, Cb + 1048576, Cb + 2097152, Qb, Kb, Vb);
    attn_fwd<<<dim3(512, 1, 1), dim3(512, 1, 1), 0, stream>>>(Qb, Kb, Vb, mask, Cb);
    cvt_w<<<dim3(512, 1), blk, 0, stream>>>(wo, wo, wo, Qb);
    gemm_nt<1, 1><<<dim3(32, 8, 1), blk, 0, stream>>>(
        Cb, Cb, Cb, Qb, Qb, Qb, out, out, out);
}

// Round 16
// 136.442 us; speedup vs baseline: 1.1496x; 1.0210x over previous
//
#include <hip/hip_runtime.h>
#include <hip/hip_bf16.h>

// MHA forward. f32 inputs (+int32 mask), f32 output; bf16 internal pipeline.
// B=2, S=2048, D_MODEL=1024, H=16, DK=64.
// [cvt weights->bf16] -> [QKV proj GEMM z=3 (Q scaled 0.125*log2e; V transposed
// via LDS-transpose epilogue), T14 prefetch] -> [flash attn: 4-wave x 2 q-groups
// (LDS reads shared across groups), LDS dbuf 1-barrier/tile, defer-max] ->
// [cvt wo] -> [O proj].

typedef short short8  __attribute__((ext_vector_type(8)));
typedef short short4v __attribute__((ext_vector_type(4)));
typedef float f32x4   __attribute__((ext_vector_type(4)));

#define D_MODEL 1024
#define SEQ     2048
#define NHEAD   16
#define DKD     64
#define HSTR    (SEQ * DKD)
#define QSCALE  0.1803368801111204f   // 0.125 * log2(e): exp2-domain softmax
#define EXP2F(x) exp2f(x)

#define MFMA16(a, b, c) __builtin_amdgcn_mfma_f32_16x16x32_bf16((a), (b), (c), 0, 0, 0)

__device__ __forceinline__ ushort f2bf(float f) {
    __hip_bfloat16 h = __float2bfloat16(f);   // RNE
    return __builtin_bit_cast(ushort, h);
}

__device__ __forceinline__ short8 frag128(const ushort* base, int row, int c0) {
    int cb = (c0 * 2) ^ ((row & 7) << 4);
    return *(const short8*)((const char*)base + row * 128 + cb);
}
__device__ __forceinline__ short8 frag256(const ushort* base, int row, int c0) {
    int cb = (c0 * 2) ^ ((row & 7) << 4);
    return *(const short8*)((const char*)base + row * 256 + cb);
}

// ---------------------------------------------------------------------------
// f32 -> bf16 weight pre-convert: 1M elems per z-slice. grid (512, nz) x 256.
// ---------------------------------------------------------------------------
__global__ __launch_bounds__(256) void cvt_w(
    const float* __restrict__ s0, const float* __restrict__ s1, const float* __restrict__ s2,
    ushort* __restrict__ dst)
{
    const int z = blockIdx.y;
    const float* s = (z == 0) ? s0 : ((z == 1) ? s1 : s2);
    ushort* d = dst + (size_t)z * 1048576;
    const int i = (blockIdx.x * 256 + threadIdx.x) * 8;
    f32x4 a = *(const f32x4*)(s + i);
    f32x4 b = *(const f32x4*)(s + i + 4);
    short8 o;
    #pragma unroll
    for (int u = 0; u < 4; ++u) { o[u] = (short)f2bf(a[u]); o[4 + u] = (short)f2bf(b[u]); }
    *(short8*)(d + i) = o;
}

// ---------------------------------------------------------------------------
// GEMM (round-13 version): C[4096][1024] = A * W^T. W bf16, reg-staged dbuf-free.
// LAYOUT 0 (QKV): z==0 -> head-split bf16 scaled QSCALE (Q); z==1 -> head-split (K);
//                 z==2 -> transposed bf16 [bh][dk][s] via LDS-transpose epilogue (V).
// LAYOUT 1: plain f32 out[m*1024+n] (O-proj).
// ---------------------------------------------------------------------------
template<int LAYOUT, int A_BF16>
__global__ __launch_bounds__(256, 3) void gemm_nt(
    const void* __restrict__ A0, const void* __restrict__ A1, const void* __restrict__ A2,
    const ushort* __restrict__ W0, const ushort* __restrict__ W1, const ushort* __restrict__ W2,
    void* __restrict__ O0, void* __restrict__ O1, void* __restrict__ O2)
{
    const int z = blockIdx.z;
    const void*   A = (z == 0) ? A0 : ((z == 1) ? A1 : A2);
    const ushort* W = (z == 0) ? W0 : ((z == 1) ? W1 : W2);
    void* O         = (z == 0) ? O0 : ((z == 1) ? O1 : O2);

    const int bm = blockIdx.x * 128;
    const int bn = blockIdx.y * 128;
    const int tid = threadIdx.x;
    const int w = tid >> 6, l = tid & 63;
    const int wr = w >> 1, wc = w & 1;

    __shared__ ushort sm[16384];

    f32x4 acc[4][4] = {};
    short8 areg[4], wreg[4];
    const int srow = tid >> 3;
    const int sc8  = (tid & 7) << 3;
    const int scb  = (sc8 * 2);

    #define GLOADT(t_) {                                                                    \
        _Pragma("unroll")                                                                   \
        for (int i = 0; i < 4; ++i) {                                                       \
            int row = i * 32 + srow;                                                        \
            if (A_BF16) {                                                                   \
                areg[i] = *(const short8*)((const ushort*)A + (size_t)(bm + row) * 1024 + (t_) * 64 + sc8); \
            } else {                                                                        \
                const float* ap = (const float*)A + (size_t)(bm + row) * 1024 + (t_) * 64 + sc8; \
                f32x4 x0 = *(const f32x4*)ap, x1 = *(const f32x4*)(ap + 4);                 \
                _Pragma("unroll")                                                           \
                for (int u = 0; u < 4; ++u) { areg[i][u] = (short)f2bf(x0[u]); areg[i][4 + u] = (short)f2bf(x1[u]); } \
            }                                                                               \
            wreg[i] = *(const short8*)(W + (size_t)(bn + row) * 1024 + (t_) * 64 + sc8);    \
        } }

    #define GWRITET() {                                                                     \
        _Pragma("unroll")                                                                   \
        for (int i = 0; i < 4; ++i) {                                                       \
            int row = i * 32 + srow;                                                        \
            int cb  = scb ^ ((row & 7) << 4);                                               \
            *(short8*)((char*)sm + row * 128 + cb) = areg[i];                               \
            *(short8*)((char*)(sm + 8192) + row * 128 + cb) = wreg[i];                      \
        } }

    GLOADT(0);
    #pragma unroll 1
    for (int t = 0; t < 16; ++t) {
        GWRITET();
        __syncthreads();
        if (t < 15) GLOADT(t + 1);

        #pragma unroll
        for (int kk = 0; kk < 2; ++kk) {
            const int c0 = kk * 32 + ((l >> 4) << 3);
            short8 af[4], bf[4];
            #pragma unroll
            for (int mi = 0; mi < 4; ++mi)
                af[mi] = frag128(sm, wr * 64 + mi * 16 + (l & 15), c0);
            #pragma unroll
            for (int ni = 0; ni < 4; ++ni)
                bf[ni] = frag128(sm + 8192, wc * 64 + ni * 16 + (l & 15), c0);
            #pragma unroll
            for (int mi = 0; mi < 4; ++mi)
                #pragma unroll
                for (int ni = 0; ni < 4; ++ni)
                    acc[mi][ni] = MFMA16(af[mi], bf[ni], acc[mi][ni]);
        }
        __syncthreads();
    }
    #undef GLOADT
    #undef GWRITET

    if (LAYOUT == 0 && z == 2) {
        // V epilogue: transpose in LDS, write [bh][dk][s] with 128B-contiguous runs.
        #pragma unroll
        for (int mi = 0; mi < 4; ++mi) {
            #pragma unroll
            for (int ni = 0; ni < 4; ++ni) {
                int n_l = wc * 64 + ni * 16 + (l & 15);
                int m0  = wr * 64 + mi * 16 + ((l >> 4) << 2);
                short4v v4;
                #pragma unroll
                for (int j = 0; j < 4; ++j) v4[j] = (short)f2bf(acc[mi][ni][j]);
                *(short4v*)((char*)sm + n_l * 256 + ((m0 * 2) ^ ((n_l & 7) << 4))) = v4;
            }
        }
        __syncthreads();
        const int row = tid >> 1, half = tid & 1;
        const int n_g = bn + row;
        const int bb  = bm >> 11;
        ushort* Op = (ushort*)O + (size_t)(bb * NHEAD + (n_g >> 6)) * HSTR
                     + (size_t)(n_g & 63) * SEQ + (bm & 2047) + half * 64;
        #pragma unroll
        for (int u = 0; u < 8; ++u) {
            short8 c = *(const short8*)((char*)sm + row * 256
                        + (((half * 64 + u * 8) * 2) ^ ((row & 7) << 4)));
            *(short8*)(Op + u * 8) = c;
        }
        return;
    }

    const float sc = (LAYOUT == 0 && z == 0) ? QSCALE : 1.0f;
    #pragma unroll
    for (int mi = 0; mi < 4; ++mi) {
        #pragma unroll
        for (int ni = 0; ni < 4; ++ni) {
            #pragma unroll
            for (int j = 0; j < 4; ++j) {
                int m = bm + wr * 64 + mi * 16 + ((l >> 4) << 2) + j;
                int n = bn + wc * 64 + ni * 16 + (l & 15);
                if (LAYOUT == 0) {
                    int b = m >> 11, s = m & 2047, h = n >> 6, dk = n & 63;
                    ((ushort*)O)[(size_t)(b * NHEAD + h) * HSTR + s * DKD + dk] = f2bf(acc[mi][ni][j] * sc);
                } else {
                    ((float*)O)[(size_t)m * 1024 + n] = acc[mi][ni][j];
                }
            }
        }
    }
}

// ---------------------------------------------------------------------------
// Flash attention. 256 thr = 4 waves; each wave owns TWO 16-row q-groups
// (32 q-rows) so every K/V fragment read from LDS feeds 2 MFMAs (halves LDS
// read volume per FLOP vs r13). QBLK=128, KVBLK=128, LDS dbuf 64KB,
// 1 barrier/tile, swapped QK^T, exp2-domain in-register softmax, defer-max
// THR=8. Grid 512 (XCD-chunked).
// ---------------------------------------------------------------------------
__global__ __launch_bounds__(256, 2) void attn_fwd(
    const ushort* __restrict__ Q, const ushort* __restrict__ K, const ushort* __restrict__ Vt,
    const int* __restrict__ mask, ushort* __restrict__ ctx)
{
    const int tid = threadIdx.x;
    const int w = tid >> 6, l = tid & 63;
    const int hi = l >> 4, lo = l & 15;
    const int id  = blockIdx.x;
    const int nid = (id & 7) * 64 + (id >> 3);     // 8 XCDs x 64 blocks
    const int bh  = nid >> 4;
    const int q0  = (nid & 15) * 128;
    const int b   = bh >> 4, h = bh & 15;

    __shared__ ushort sm[2][16384];  // per buf: K [128][64] swz @0; V [64][128] swz @8192
    __shared__ int mflag;

    if (tid == 0) mflag = 1;
    __syncthreads();
    {
        const int4* mp = ((const int4*)(mask + b * SEQ)) + tid;
        int4 m0 = mp[0], m1 = mp[256];
        if (!(m0.x && m0.y && m0.z && m0.w && m1.x && m1.y && m1.z && m1.w)) mflag = 0;
    }

    const ushort* Qh = Q  + (size_t)bh * HSTR;
    const ushort* Kh = K  + (size_t)bh * HSTR;
    const ushort* Vh = Vt + (size_t)bh * HSTR;     // [dk][s]

    // Q frags (B operand), two groups: q = q0 + w*32 + g*16 + lo
    short8 qf[2][2];
    #pragma unroll
    for (int g = 0; g < 2; ++g)
        #pragma unroll
        for (int kk = 0; kk < 2; ++kk)
            qf[g][kk] = *(const short8*)(Qh + (size_t)(q0 + w * 32 + g * 16 + lo) * DKD
                                         + kk * 32 + hi * 8);

    f32x4 acc[2][4] = {};
    float m_run[2] = {-INFINITY, -INFINITY}, l_run[2] = {0.0f, 0.0f};

    // staging (256 thr): K 4x16B/thread, V 4x(8+8)B/thread (kphys perm)
    const int kr = tid >> 3;               // 0..31
    const int kc = (tid & 7) << 3;
    const int vr = tid >> 4;               // 0..15
    const int vkpb = (tid & 15) << 4;

    short8  kreg[4];
    short4v vreg0[4], vreg1[4];

    #define LOADT(kt_) {                                                                   \
        _Pragma("unroll")                                                                  \
        for (int i = 0; i < 4; ++i)                                                        \
            kreg[i] = *(const short8*)(Kh + (size_t)((kt_) * 128 + i * 32 + kr) * DKD + kc); \
        _Pragma("unroll")                                                                  \
        for (int i = 0; i < 4; ++i) {                                                      \
            const ushort* vp = Vh + (size_t)(i * 16 + vr) * SEQ + (kt_) * 128 + ((tid >> 2) & 3) * 32 + (tid & 3) * 4; \
            vreg0[i] = *(const short4v*)(vp);                                              \
            vreg1[i] = *(const short4v*)(vp + 16); } }

    #define WRITET(buf_) {                                                                 \
        _Pragma("unroll")                                                                  \
        for (int i = 0; i < 4; ++i) {                                                      \
            int r = i * 32 + kr;                                                           \
            *(short8*)((char*)sm[buf_] + r * 128 + ((kc * 2) ^ ((r & 7) << 4))) = kreg[i]; } \
        _Pragma("unroll")                                                                  \
        for (int i = 0; i < 4; ++i) {                                                      \
            int r = i * 16 + vr;                                                           \
            char* p = (char*)(sm[buf_] + 8192) + r * 256 + (vkpb ^ ((r & 7) << 4));        \
            *(short4v*)(p)     = vreg0[i];                                                 \
            *(short4v*)(p + 8) = vreg1[i]; } }

    LOADT(0); WRITET(0);
    __syncthreads();                       // buf0 staged + mflag final
    const bool allones = (mflag != 0);
    const f32x4 zf = {};

    // softmax for group g_ over full 128-kv tile; packs pa[g_]
    #define SMG(g_) {                                                                      \
        if (!allones) {                                                                    \
            const int* mrow = mask + b * SEQ + kt * 128 + hi * 4;                          \
            _Pragma("unroll")                                                              \
            for (int ni = 0; ni < 8; ++ni) {                                               \
                int4 mv = *(const int4*)(mrow + ni * 16);                                  \
                s4[g_][ni][0] = mv.x ? s4[g_][ni][0] : -1e9f;                              \
                s4[g_][ni][1] = mv.y ? s4[g_][ni][1] : -1e9f;                              \
                s4[g_][ni][2] = mv.z ? s4[g_][ni][2] : -1e9f;                              \
                s4[g_][ni][3] = mv.w ? s4[g_][ni][3] : -1e9f;                              \
            }                                                                              \
        }                                                                                  \
        float t = fmaxf(fmaxf(s4[g_][0][0], s4[g_][0][1]), fmaxf(s4[g_][0][2], s4[g_][0][3])); \
        _Pragma("unroll")                                                                  \
        for (int ni = 1; ni < 8; ++ni) {                                                   \
            float tn = fmaxf(fmaxf(s4[g_][ni][0], s4[g_][ni][1]),                          \
                             fmaxf(s4[g_][ni][2], s4[g_][ni][3]));                         \
            t = fmaxf(t, tn);                                                              \
        }                                                                                  \
        t = fmaxf(t, __shfl_xor(t, 16));                                                   \
        t = fmaxf(t, __shfl_xor(t, 32));                                                   \
        if (!__all(t <= m_run[g_] + 8.0f)) {                                               \
            float mnew = fmaxf(m_run[g_], t);                                              \
            float c = EXP2F(m_run[g_] - mnew);                                             \
            m_run[g_] = mnew;                                                              \
            l_run[g_] *= c;                                                                \
            float cj[4];                                                                   \
            _Pragma("unroll")                                                              \
            for (int j = 0; j < 4; ++j) cj[j] = __shfl(c, (l & 48) | (hi * 4 + j));        \
            _Pragma("unroll")                                                              \
            for (int ni = 0; ni < 4; ++ni)                                                 \
                _Pragma("unroll")                                                          \
                for (int j = 0; j < 4; ++j) acc[g_][ni][j] *= cj[j];                       \
        }                                                                                  \
        float rs = 0.0f;                                                                   \
        _Pragma("unroll")                                                                  \
        for (int ni = 0; ni < 8; ++ni) {                                                   \
            _Pragma("unroll")                                                              \
            for (int j = 0; j < 4; ++j) s4[g_][ni][j] = EXP2F(s4[g_][ni][j] - m_run[g_]);  \
            rs += (s4[g_][ni][0] + s4[g_][ni][1]) + (s4[g_][ni][2] + s4[g_][ni][3]);       \
        }                                                                                  \
        rs += __shfl_xor(rs, 16);                                                          \
        rs += __shfl_xor(rs, 32);                                                          \
        l_run[g_] += rs;                                                                   \
        _Pragma("unroll")                                                                  \
        for (int kk = 0; kk < 4; ++kk)                                                     \
            _Pragma("unroll")                                                              \
            for (int j = 0; j < 4; ++j) {                                                  \
                pa[g_][kk][j]     = (short)f2bf(s4[g_][2 * kk][j]);                        \
                pa[g_][kk][4 + j] = (short)f2bf(s4[g_][2 * kk + 1][j]);                    \
            } }

    #pragma unroll 1
    for (int kt = 0; kt < 16; ++kt) {
        const int cur = kt & 1;
        const ushort* kb = sm[cur];
        const ushort* vb = sm[cur] + 8192;

        if (kt < 15) LOADT(kt + 1);        // global->regs, lands under QK^T+SM

        // QK^T both groups, shared K-frag reads. C-layout: kv = ni*16+hi*4+j, q = lo.
        f32x4 s4[2][8];
        __builtin_amdgcn_s_setprio(1);
        #pragma unroll
        for (int ni = 0; ni < 8; ++ni) {
            short8 kf = frag128(kb, ni * 16 + lo, hi * 8);
            s4[0][ni] = MFMA16(kf, qf[0][0], zf);
            s4[1][ni] = MFMA16(kf, qf[1][0], zf);
        }
        #pragma unroll
        for (int ni = 0; ni < 8; ++ni) {
            short8 kf = frag128(kb, ni * 16 + lo, 32 + hi * 8);
            s4[0][ni] = MFMA16(kf, qf[0][1], s4[0][ni]);
            s4[1][ni] = MFMA16(kf, qf[1][1], s4[1][ni]);
        }
        __builtin_amdgcn_s_setprio(0);

        short8 pa[2][4];
        SMG(0)
        SMG(1)

        if (kt < 15) WRITET(cur ^ 1);      // regs->other buffer

        // PV both groups, shared V-frag reads. acc C-layout: q = hi*4+j, dk = ni*16+lo.
        __builtin_amdgcn_s_setprio(1);
        #pragma unroll
        for (int kk = 0; kk < 4; ++kk) {
            const int c0 = kk * 32 + hi * 8;
            #pragma unroll
            for (int ni = 0; ni < 4; ++ni) {
                short8 vf = frag256(vb, ni * 16 + lo, c0);
                acc[0][ni] = MFMA16(pa[0][kk], vf, acc[0][ni]);
                acc[1][ni] = MFMA16(pa[1][kk], vf, acc[1][ni]);
            }
        }
        __builtin_amdgcn_s_setprio(0);

        __syncthreads();                   // buf[cur] reads + buf[cur^1] writes done
    }
    #undef SMG
    #undef LOADT
    #undef WRITET

    #pragma unroll
    for (int g = 0; g < 2; ++g) {
        float inv = 1.0f / l_run[g];
        float invj[4];
        #pragma unroll
        for (int j = 0; j < 4; ++j)
            invj[j] = __shfl(inv, (l & 48) | (hi * 4 + j));
        #pragma unroll
        for (int ni = 0; ni < 4; ++ni)
            #pragma unroll
            for (int j = 0; j < 4; ++j) {
                int qg = q0 + w * 32 + g * 16 + hi * 4 + j;
                ctx[(size_t)(b * SEQ + qg) * D_MODEL + h * DKD + ni * 16 + lo] =
                    f2bf(acc[g][ni][j] * invj[j]);
            }
    }
}

__global__ void ws_sentinel(float* __restrict__ out, int n, float code) {
    int i = blockIdx.x * blockDim.x + threadIdx.x;
    if (i < n) out[i] = (i == 0) ? code : 0.0f;
}

// ---------------------------------------------------------------------------
extern "C" void kernel_launch(void* const* d_in, const int* in_sizes, int n_in,
                              void* d_out, int out_size, void* d_ws, size_t ws_size,
                              hipStream_t stream) {
    const float* q    = (const float*)d_in[0];
    const float* k    = (const float*)d_in[1];
    const float* v    = (const float*)d_in[2];
    const int*   mask = (const int*)d_in[3];
    const float* wq   = (const float*)d_in[4];
    const float* wk   = (const float*)d_in[5];
    const float* wv   = (const float*)d_in[6];
    const float* wo   = (const float*)d_in[7];
    float* out = (float*)d_out;

    if (ws_size < (size_t)33554432) {
        float code = 100.0f + (float)(ws_size >> 20);
        ws_sentinel<<<(out_size + 255) / 256, 256, 0, stream>>>(out, out_size, code);
        return;
    }

    ushort* ws = (ushort*)d_ws;
    ushort* Qb = ws;                       // [bh][s][dk] bf16 (scaled QSCALE); later: wo bf16
    ushort* Kb = ws + 4194304;             // [bh][s][dk]
    ushort* Vb = ws + 8388608;             // [bh][dk][s]  (transposed)
    ushort* Cb = ws + 12582912;            // first: wq/wk/wv bf16; then context [b,s,d] bf16

    dim3 blk(256, 1, 1);
    cvt_w<<<dim3(512, 3), blk, 0, stream>>>(wq, wk, wv, Cb);
    gemm_nt<0, 0><<<dim3(32, 8, 3), blk, 0, stream>>>(
        q, k, v, Cb, Cb + 1048576, Cb + 2097152, Qb, Kb, Vb);
    attn_fwd<<<dim3(512, 1, 1), blk, 0, stream>>>(Qb, Kb, Vb, mask, Cb);
    cvt_w<<<dim3(512, 1), blk, 0, stream>>>(wo, wo, wo, Qb);
    gemm_nt<1, 1><<<dim3(32, 8, 1), blk, 0, stream>>>(
        Cb, Cb, Cb, Qb, Qb, Qb, out, out, out);
}

// Round 17
// 121.622 us; speedup vs baseline: 1.2897x; 1.1219x over previous
//
#include <hip/hip_runtime.h>
#include <hip/hip_bf16.h>

// MHA forward. f32 inputs (+int32 mask), f32 output; bf16 internal pipeline.
// B=2, S=2048, D_MODEL=1024, H=16, DK=64.
// [cvt weights->bf16] -> [QKV proj GEMM z=3 (Q scaled 0.125*log2e; V transposed
// via LDS-transpose epilogue), T14 prefetch] -> [flash attn r13: 8-wave QBLK=128,
// LDS dbuf 1-barrier/tile, defer-max; R17: exp via __builtin_amdgcn_exp2f
// (single v_exp_f32, replaces multi-inst libm exp2f)] -> [cvt wo] -> [O proj].

typedef short short8  __attribute__((ext_vector_type(8)));
typedef short short4v __attribute__((ext_vector_type(4)));
typedef float f32x4   __attribute__((ext_vector_type(4)));

#define D_MODEL 1024
#define SEQ     2048
#define NHEAD   16
#define DKD     64
#define HSTR    (SEQ * DKD)
#define QSCALE  0.1803368801111204f   // 0.125 * log2(e): exp2-domain softmax
#define EXP2F(x) __builtin_amdgcn_exp2f(x)   // raw v_exp_f32 (base-2 HW exp)

#define MFMA16(a, b, c) __builtin_amdgcn_mfma_f32_16x16x32_bf16((a), (b), (c), 0, 0, 0)

__device__ __forceinline__ ushort f2bf(float f) {
    __hip_bfloat16 h = __float2bfloat16(f);   // RNE
    return __builtin_bit_cast(ushort, h);
}

__device__ __forceinline__ short8 frag128(const ushort* base, int row, int c0) {
    int cb = (c0 * 2) ^ ((row & 7) << 4);
    return *(const short8*)((const char*)base + row * 128 + cb);
}
__device__ __forceinline__ short8 frag256(const ushort* base, int row, int c0) {
    int cb = (c0 * 2) ^ ((row & 7) << 4);
    return *(const short8*)((const char*)base + row * 256 + cb);
}

// ---------------------------------------------------------------------------
// f32 -> bf16 weight pre-convert: 1M elems per z-slice. grid (512, nz) x 256.
// ---------------------------------------------------------------------------
__global__ __launch_bounds__(256) void cvt_w(
    const float* __restrict__ s0, const float* __restrict__ s1, const float* __restrict__ s2,
    ushort* __restrict__ dst)
{
    const int z = blockIdx.y;
    const float* s = (z == 0) ? s0 : ((z == 1) ? s1 : s2);
    ushort* d = dst + (size_t)z * 1048576;
    const int i = (blockIdx.x * 256 + threadIdx.x) * 8;
    f32x4 a = *(const f32x4*)(s + i);
    f32x4 b = *(const f32x4*)(s + i + 4);
    short8 o;
    #pragma unroll
    for (int u = 0; u < 4; ++u) { o[u] = (short)f2bf(a[u]); o[4 + u] = (short)f2bf(b[u]); }
    *(short8*)(d + i) = o;
}

// ---------------------------------------------------------------------------
// GEMM (round-13 version): C[4096][1024] = A * W^T. W bf16, reg-staged.
// LAYOUT 0 (QKV): z==0 -> head-split bf16 scaled QSCALE (Q); z==1 -> head-split (K);
//                 z==2 -> transposed bf16 [bh][dk][s] via LDS-transpose epilogue (V).
// LAYOUT 1: plain f32 out[m*1024+n] (O-proj).
// ---------------------------------------------------------------------------
template<int LAYOUT, int A_BF16>
__global__ __launch_bounds__(256, 3) void gemm_nt(
    const void* __restrict__ A0, const void* __restrict__ A1, const void* __restrict__ A2,
    const ushort* __restrict__ W0, const ushort* __restrict__ W1, const ushort* __restrict__ W2,
    void* __restrict__ O0, void* __restrict__ O1, void* __restrict__ O2)
{
    const int z = blockIdx.z;
    const void*   A = (z == 0) ? A0 : ((z == 1) ? A1 : A2);
    const ushort* W = (z == 0) ? W0 : ((z == 1) ? W1 : W2);
    void* O         = (z == 0) ? O0 : ((z == 1) ? O1 : O2);

    const int bm = blockIdx.x * 128;
    const int bn = blockIdx.y * 128;
    const int tid = threadIdx.x;
    const int w = tid >> 6, l = tid & 63;
    const int wr = w >> 1, wc = w & 1;

    __shared__ ushort sm[16384];

    f32x4 acc[4][4] = {};
    short8 areg[4], wreg[4];
    const int srow = tid >> 3;
    const int sc8  = (tid & 7) << 3;
    const int scb  = (sc8 * 2);

    #define GLOADT(t_) {                                                                    \
        _Pragma("unroll")                                                                   \
        for (int i = 0; i < 4; ++i) {                                                       \
            int row = i * 32 + srow;                                                        \
            if (A_BF16) {                                                                   \
                areg[i] = *(const short8*)((const ushort*)A + (size_t)(bm + row) * 1024 + (t_) * 64 + sc8); \
            } else {                                                                        \
                const float* ap = (const float*)A + (size_t)(bm + row) * 1024 + (t_) * 64 + sc8; \
                f32x4 x0 = *(const f32x4*)ap, x1 = *(const f32x4*)(ap + 4);                 \
                _Pragma("unroll")                                                           \
                for (int u = 0; u < 4; ++u) { areg[i][u] = (short)f2bf(x0[u]); areg[i][4 + u] = (short)f2bf(x1[u]); } \
            }                                                                               \
            wreg[i] = *(const short8*)(W + (size_t)(bn + row) * 1024 + (t_) * 64 + sc8);    \
        } }

    #define GWRITET() {                                                                     \
        _Pragma("unroll")                                                                   \
        for (int i = 0; i < 4; ++i) {                                                       \
            int row = i * 32 + srow;                                                        \
            int cb  = scb ^ ((row & 7) << 4);                                               \
            *(short8*)((char*)sm + row * 128 + cb) = areg[i];                               \
            *(short8*)((char*)(sm + 8192) + row * 128 + cb) = wreg[i];                      \
        } }

    GLOADT(0);
    #pragma unroll 1
    for (int t = 0; t < 16; ++t) {
        GWRITET();
        __syncthreads();
        if (t < 15) GLOADT(t + 1);

        #pragma unroll
        for (int kk = 0; kk < 2; ++kk) {
            const int c0 = kk * 32 + ((l >> 4) << 3);
            short8 af[4], bf[4];
            #pragma unroll
            for (int mi = 0; mi < 4; ++mi)
                af[mi] = frag128(sm, wr * 64 + mi * 16 + (l & 15), c0);
            #pragma unroll
            for (int ni = 0; ni < 4; ++ni)
                bf[ni] = frag128(sm + 8192, wc * 64 + ni * 16 + (l & 15), c0);
            #pragma unroll
            for (int mi = 0; mi < 4; ++mi)
                #pragma unroll
                for (int ni = 0; ni < 4; ++ni)
                    acc[mi][ni] = MFMA16(af[mi], bf[ni], acc[mi][ni]);
        }
        __syncthreads();
    }
    #undef GLOADT
    #undef GWRITET

    if (LAYOUT == 0 && z == 2) {
        // V epilogue: transpose in LDS, write [bh][dk][s] with 128B-contiguous runs.
        #pragma unroll
        for (int mi = 0; mi < 4; ++mi) {
            #pragma unroll
            for (int ni = 0; ni < 4; ++ni) {
                int n_l = wc * 64 + ni * 16 + (l & 15);
                int m0  = wr * 64 + mi * 16 + ((l >> 4) << 2);
                short4v v4;
                #pragma unroll
                for (int j = 0; j < 4; ++j) v4[j] = (short)f2bf(acc[mi][ni][j]);
                *(short4v*)((char*)sm + n_l * 256 + ((m0 * 2) ^ ((n_l & 7) << 4))) = v4;
            }
        }
        __syncthreads();
        const int row = tid >> 1, half = tid & 1;
        const int n_g = bn + row;
        const int bb  = bm >> 11;
        ushort* Op = (ushort*)O + (size_t)(bb * NHEAD + (n_g >> 6)) * HSTR
                     + (size_t)(n_g & 63) * SEQ + (bm & 2047) + half * 64;
        #pragma unroll
        for (int u = 0; u < 8; ++u) {
            short8 c = *(const short8*)((char*)sm + row * 256
                        + (((half * 64 + u * 8) * 2) ^ ((row & 7) << 4)));
            *(short8*)(Op + u * 8) = c;
        }
        return;
    }

    const float sc = (LAYOUT == 0 && z == 0) ? QSCALE : 1.0f;
    #pragma unroll
    for (int mi = 0; mi < 4; ++mi) {
        #pragma unroll
        for (int ni = 0; ni < 4; ++ni) {
            #pragma unroll
            for (int j = 0; j < 4; ++j) {
                int m = bm + wr * 64 + mi * 16 + ((l >> 4) << 2) + j;
                int n = bn + wc * 64 + ni * 16 + (l & 15);
                if (LAYOUT == 0) {
                    int b = m >> 11, s = m & 2047, h = n >> 6, dk = n & 63;
                    ((ushort*)O)[(size_t)(b * NHEAD + h) * HSTR + s * DKD + dk] = f2bf(acc[mi][ni][j] * sc);
                } else {
                    ((float*)O)[(size_t)m * 1024 + n] = acc[mi][ni][j];
                }
            }
        }
    }
}

// ---------------------------------------------------------------------------
// Flash attention (r13 structure). 512 thr = 8 waves, QBLK=128 (16 q-rows/wave),
// KVBLK=128, LDS double-buffer (64 KB) -> ONE barrier per tile. Swapped QK^T,
// exp2-domain in-register softmax (HW v_exp_f32), defer-max THR=8, zero-C MFMA
// s4 init. Grid 512 (XCD-chunked, 2 bh per XCD).
// ---------------------------------------------------------------------------
__global__ __launch_bounds__(512, 4) void attn_fwd(
    const ushort* __restrict__ Q, const ushort* __restrict__ K, const ushort* __restrict__ Vt,
    const int* __restrict__ mask, ushort* __restrict__ ctx)
{
    const int tid = threadIdx.x;
    const int w = tid >> 6, l = tid & 63;
    const int hi = l >> 4, lo = l & 15;
    const int id  = blockIdx.x;
    const int nid = (id & 7) * 64 + (id >> 3);     // 8 XCDs x 64 blocks
    const int bh  = nid >> 4;
    const int q0  = (nid & 15) * 128;
    const int b   = bh >> 4, h = bh & 15;

    __shared__ ushort sm[2][16384];  // per buf: K [128][64] swz @0; V [64][128] swz @8192
    __shared__ int mflag;

    if (tid == 0) mflag = 1;
    __syncthreads();
    {
        int4 m0 = ((const int4*)(mask + b * SEQ))[tid];
        if (!(m0.x && m0.y && m0.z && m0.w)) mflag = 0;
    }

    const ushort* Qh = Q  + (size_t)bh * HSTR;
    const ushort* Kh = K  + (size_t)bh * HSTR;
    const ushort* Vh = Vt + (size_t)bh * HSTR;     // [dk][s]

    short8 qf[2];
    #pragma unroll
    for (int kk = 0; kk < 2; ++kk)
        qf[kk] = *(const short8*)(Qh + (size_t)(q0 + w * 16 + lo) * DKD + kk * 32 + hi * 8);

    f32x4 acc_o[4] = {};
    float m_run = -INFINITY, l_run = 0.0f;

    const int kr = tid >> 3;               // 0..63
    const int kc = (tid & 7) << 3;
    const int vr = tid >> 4;               // 0..31
    const int vkpb = (tid & 15) << 4;

    short8  kreg[2];
    short4v vreg0[2], vreg1[2];

    #define LOADT(kt_) {                                                                   \
        _Pragma("unroll")                                                                  \
        for (int i = 0; i < 2; ++i)                                                        \
            kreg[i] = *(const short8*)(Kh + (size_t)((kt_) * 128 + i * 64 + kr) * DKD + kc); \
        _Pragma("unroll")                                                                  \
        for (int i = 0; i < 2; ++i) {                                                      \
            const ushort* vp = Vh + (size_t)(i * 32 + vr) * SEQ + (kt_) * 128 + ((tid >> 2) & 3) * 32 + (tid & 3) * 4; \
            vreg0[i] = *(const short4v*)(vp);                                              \
            vreg1[i] = *(const short4v*)(vp + 16); } }

    #define WRITET(buf_) {                                                                 \
        _Pragma("unroll")                                                                  \
        for (int i = 0; i < 2; ++i) {                                                      \
            int r = i * 64 + kr;                                                           \
            *(short8*)((char*)sm[buf_] + r * 128 + ((kc * 2) ^ ((r & 7) << 4))) = kreg[i]; } \
        _Pragma("unroll")                                                                  \
        for (int i = 0; i < 2; ++i) {                                                      \
            int r = i * 32 + vr;                                                           \
            char* p = (char*)(sm[buf_] + 8192) + r * 256 + (vkpb ^ ((r & 7) << 4));        \
            *(short4v*)(p)     = vreg0[i];                                                 \
            *(short4v*)(p + 8) = vreg1[i]; } }

    LOADT(0); WRITET(0);
    __syncthreads();                       // buf0 staged + mflag final
    const bool allones = (mflag != 0);
    const f32x4 zf = {};

    #define HALF(nb_) {                                                                    \
        f32x4* s = s4 + 4 * (nb_);                                                         \
        if (!allones) {                                                                    \
            const int* mrow = mask + b * SEQ + kt * 128 + (nb_) * 64 + hi * 4;             \
            _Pragma("unroll")                                                              \
            for (int ni = 0; ni < 4; ++ni) {                                               \
                int4 mv = *(const int4*)(mrow + ni * 16);                                  \
                s[ni][0] = mv.x ? s[ni][0] : -1e9f;                                        \
                s[ni][1] = mv.y ? s[ni][1] : -1e9f;                                        \
                s[ni][2] = mv.z ? s[ni][2] : -1e9f;                                        \
                s[ni][3] = mv.w ? s[ni][3] : -1e9f;                                        \
            }                                                                              \
        }                                                                                  \
        float t0 = fmaxf(fmaxf(s[0][0], s[0][1]), fmaxf(s[0][2], s[0][3]));                \
        float t1 = fmaxf(fmaxf(s[1][0], s[1][1]), fmaxf(s[1][2], s[1][3]));                \
        float t2 = fmaxf(fmaxf(s[2][0], s[2][1]), fmaxf(s[2][2], s[2][3]));                \
        float t3 = fmaxf(fmaxf(s[3][0], s[3][1]), fmaxf(s[3][2], s[3][3]));                \
        float t = fmaxf(fmaxf(t0, t1), fmaxf(t2, t3));                                     \
        t = fmaxf(t, __shfl_xor(t, 16));                                                   \
        t = fmaxf(t, __shfl_xor(t, 32));                                                   \
        if (!__all(t <= m_run + 8.0f)) {   /* defer-max: rescale only on real growth */    \
            float mnew = fmaxf(m_run, t);                                                  \
            float c = EXP2F(m_run - mnew);                                                 \
            m_run = mnew;                                                                  \
            l_run *= c;                                                                    \
            float cj[4];                                                                   \
            _Pragma("unroll")                                                              \
            for (int j = 0; j < 4; ++j) cj[j] = __shfl(c, (l & 48) | (hi * 4 + j));        \
            _Pragma("unroll")                                                              \
            for (int ni = 0; ni < 4; ++ni)                                                 \
                _Pragma("unroll")                                                          \
                for (int j = 0; j < 4; ++j) acc_o[ni][j] *= cj[j];                         \
        }                                                                                  \
        float rsA = 0.0f;                                                                  \
        _Pragma("unroll")                                                                  \
        for (int ni = 0; ni < 4; ++ni) {                                                   \
            _Pragma("unroll")                                                              \
            for (int j = 0; j < 4; ++j) s[ni][j] = EXP2F(s[ni][j] - m_run);                \
            rsA += (s[ni][0] + s[ni][1]) + (s[ni][2] + s[ni][3]);                          \
        }                                                                                  \
        rsA += __shfl_xor(rsA, 16);                                                        \
        rsA += __shfl_xor(rsA, 32);                                                        \
        l_run += rsA;                                                                      \
        short8 pa[2];                                                                      \
        _Pragma("unroll")                                                                  \
        for (int kk = 0; kk < 2; ++kk) {                                                   \
            _Pragma("unroll")                                                              \
            for (int j = 0; j < 4; ++j) {                                                  \
                pa[kk][j]     = (short)f2bf(s[2 * kk][j]);                                 \
                pa[kk][4 + j] = (short)f2bf(s[2 * kk + 1][j]);                             \
            }                                                                              \
        }                                                                                  \
        __builtin_amdgcn_s_setprio(1);                                                     \
        _Pragma("unroll")                                                                  \
        for (int kk = 0; kk < 2; ++kk) {                                                   \
            const int c0 = ((nb_) * 2 + kk) * 32 + hi * 8;                                 \
            _Pragma("unroll")                                                              \
            for (int ni = 0; ni < 4; ++ni) {                                               \
                short8 vf = frag256(vb, ni * 16 + lo, c0);                                 \
                acc_o[ni] = MFMA16(pa[kk], vf, acc_o[ni]);                                 \
            }                                                                              \
        }                                                                                  \
        __builtin_amdgcn_s_setprio(0); }

    #pragma unroll 1
    for (int kt = 0; kt < 16; ++kt) {
        const int cur = kt & 1;
        const ushort* kb = sm[cur];
        const ushort* vb = sm[cur] + 8192;

        if (kt < 15) LOADT(kt + 1);        // global->regs, lands under QK^T+SM(A)

        // QK^T: s4[ni] C-layout: kv = ni*16 + hi*4 + j, q = lo. Zero-C init.
        f32x4 s4[8];
        __builtin_amdgcn_s_setprio(1);
        #pragma unroll
        for (int ni = 0; ni < 8; ++ni)
            s4[ni] = MFMA16(frag128(kb, ni * 16 + lo, hi * 8), qf[0], zf);
        #pragma unroll
        for (int ni = 0; ni < 8; ++ni)
            s4[ni] = MFMA16(frag128(kb, ni * 16 + lo, 32 + hi * 8), qf[1], s4[ni]);
        __builtin_amdgcn_s_setprio(0);

        HALF(0)
        if (kt < 15) WRITET(cur ^ 1);      // regs->other buffer
        HALF(1)

        __syncthreads();                   // single barrier: buf[cur] reads + buf[cur^1] writes done
    }
    #undef HALF
    #undef LOADT
    #undef WRITET

    float inv = 1.0f / l_run;
    float invj[4];
    #pragma unroll
    for (int j = 0; j < 4; ++j)
        invj[j] = __shfl(inv, (l & 48) | (hi * 4 + j));
    #pragma unroll
    for (int ni = 0; ni < 4; ++ni)
        #pragma unroll
        for (int j = 0; j < 4; ++j) {
            int qg = q0 + w * 16 + hi * 4 + j;
            ctx[(size_t)(b * SEQ + qg) * D_MODEL + h * DKD + ni * 16 + lo] = f2bf(acc_o[ni][j] * invj[j]);
        }
}

__global__ void ws_sentinel(float* __restrict__ out, int n, float code) {
    int i = blockIdx.x * blockDim.x + threadIdx.x;
    if (i < n) out[i] = (i == 0) ? code : 0.0f;
}

// ---------------------------------------------------------------------------
extern "C" void kernel_launch(void* const* d_in, const int* in_sizes, int n_in,
                              void* d_out, int out_size, void* d_ws, size_t ws_size,
                              hipStream_t stream) {
    const float* q    = (const float*)d_in[0];
    const float* k    = (const float*)d_in[1];
    const float* v    = (const float*)d_in[2];
    const int*   mask = (const int*)d_in[3];
    const float* wq   = (const float*)d_in[4];
    const float* wk   = (const float*)d_in[5];
    const float* wv   = (const float*)d_in[6];
    const float* wo   = (const float*)d_in[7];
    float* out = (float*)d_out;

    if (ws_size < (size_t)33554432) {
        float code = 100.0f + (float)(ws_size >> 20);
        ws_sentinel<<<(out_size + 255) / 256, 256, 0, stream>>>(out, out_size, code);
        return;
    }

    ushort* ws = (ushort*)d_ws;
    ushort* Qb = ws;                       // [bh][s][dk] bf16 (scaled QSCALE); later: wo bf16
    ushort* Kb = ws + 4194304;             // [bh][s][dk]
    ushort* Vb = ws + 8388608;             // [bh][dk][s]  (transposed)
    ushort* Cb = ws + 12582912;            // first: wq/wk/wv bf16; then context [b,s,d] bf16

    dim3 blk(256, 1, 1);
    cvt_w<<<dim3(512, 3), blk, 0, stream>>>(wq, wk, wv, Cb);
    gemm_nt<0, 0><<<dim3(32, 8, 3), blk, 0, stream>>>(
        q, k, v, Cb, Cb + 1048576, Cb + 2097152, Qb, Kb, Vb);
    attn_fwd<<<dim3(512, 1, 1), dim3(512, 1, 1), 0, stream>>>(Qb, Kb, Vb, mask, Cb);
    cvt_w<<<dim3(512, 1), blk, 0, stream>>>(wo, wo, wo, Qb);
    gemm_nt<1, 1><<<dim3(32, 8, 1), blk, 0, stream>>>(
        Cb, Cb, Cb, Qb, Qb, Qb, out, out, out);
}